// Round 8
// baseline (38.629 us; speedup 1.0000x reference)
//
#include <hip/hip_runtime.h>
#include <hip/hip_bf16.h>

#define FFN 2048
#define LN_EPS 1e-5f

typedef __attribute__((ext_vector_type(8))) short bf16x8;
typedef __attribute__((ext_vector_type(4))) float f32x4;

union FragU { bf16x8 v; unsigned u[4]; uint4 q; };

static __device__ __forceinline__ unsigned cvtpk(float lo, float hi) {
    unsigned r;
    asm("v_cvt_pk_bf16_f32 %0, %1, %2" : "=v"(r) : "v"(lo), "v"(hi));
    return r;
}

// relu on a packed bf16 pair: sign bit position matches f16; |x| << f16-NaN range
static __device__ __forceinline__ unsigned pkrelu(unsigned a, unsigned z) {
    unsigned r;
    asm("v_pk_max_f16 %0, %1, %2" : "=v"(r) : "v"(a), "v"(z));
    return r;
}

static __device__ __forceinline__ ushort to_bf16(float f) {   // RNE, finite inputs
    unsigned u = __float_as_uint(f);
    u += 0x7fffu + ((u >> 16) & 1u);
    return (ushort)(u >> 16);
}

// ---------------- prep: bake per-lane 16x16x32 MFMA fragments (VERIFIED R3-R6) ----------------
// ws uint4 layout: [0..8191]  fragW1[cc][s][lane]   (k=8g+j; g0: W1[f][j], g1 j0: b1[f]; f=cc*32+s*16+c)
//                  [8192..12287] fragW2[cc][lane]   (k=8g+j <-> f_local = 4g+(j&3)+16*(j>>2); rows c>=8 zero)
//                  [12288..143359] mB[token]        (m as 8 bf16, written by tbq_prefix)
__global__ __launch_bounds__(256) void tbq_prep(
    const float* __restrict__ W1, const float* __restrict__ b1,
    const float* __restrict__ W2, uint4* __restrict__ ws)
{
    const int idx = blockIdx.x * 256 + threadIdx.x;
    ushort v[8] = {0,0,0,0,0,0,0,0};
    if (idx < 8192) {
        const int lane = idx & 63, s = (idx >> 6) & 1, cc = idx >> 7;
        const int c = lane & 15, g = lane >> 4;
        const int f = cc * 32 + s * 16 + c;
        if (g == 0) {
            #pragma unroll
            for (int j = 0; j < 8; ++j) v[j] = to_bf16(W1[f * 8 + j]);
        } else if (g == 1) {
            v[0] = to_bf16(b1[f]);
        }
    } else {
        const int i2 = idx - 8192;
        const int lane = i2 & 63, cc = i2 >> 6;
        const int c = lane & 15, g = lane >> 4;
        if (c < 8) {
            #pragma unroll
            for (int j = 0; j < 8; ++j) {
                const int fl = 4 * g + (j & 3) + 16 * (j >> 2);
                v[j] = to_bf16(W2[c * FFN + cc * 32 + fl]);
            }
        }
    }
    union { ushort s[8]; uint4 q; } pk;
    #pragma unroll
    for (int j = 0; j < 8; ++j) pk.s[j] = v[j];
    ws[idx] = pk.q;
}

// ---------------- prefix: one thread per token; h(f32)->out (scratch), m(bf16)->ws ----------------
__global__ __launch_bounds__(64) void tbq_prefix(
    const float* __restrict__ x,
    const float* __restrict__ Wq,
    const float* __restrict__ Wo,
    const float* __restrict__ g1,
    const float* __restrict__ beta1,
    uint4* __restrict__ mws,
    float* __restrict__ hout)
{
    const int t = blockIdx.x * 64 + threadIdx.x;
    const float4* xr = (const float4*)(x + (size_t)t * 8);
    float4 xa = xr[0], xb = xr[1];
    float xv[8] = {xa.x, xa.y, xa.z, xa.w, xb.x, xb.y, xb.z, xb.w};

    float qm[8];
    {
        float cp = 1.0f;
        #pragma unroll
        for (int f = 0; f < 8; ++f) {
            float acc = 0.0f;
            #pragma unroll
            for (int e = 0; e < 8; ++e) acc += xv[e] * Wq[f * 8 + e];
            cp *= __cosf(acc);
            qm[f] = cp;
        }
    }
    float h[8];
    float mu = 0.0f;
    #pragma unroll
    for (int f = 0; f < 8; ++f) {
        float acc = 0.0f;
        #pragma unroll
        for (int e = 0; e < 8; ++e) acc += qm[e] * Wo[f * 8 + e];
        h[f] = xv[f] + acc;
        mu += h[f];
    }
    mu *= 0.125f;
    float var = 0.0f;
    #pragma unroll
    for (int i = 0; i < 8; ++i) { float d = h[i] - mu; var += d * d; }
    var *= 0.125f;
    float rs = rsqrtf(var + LN_EPS);
    #pragma unroll
    for (int i = 0; i < 8; ++i) h[i] = (h[i] - mu) * rs * g1[i] + beta1[i];

    float m[8];
    {
        float cp = 1.0f;
        #pragma unroll
        for (int i = 0; i < 8; ++i) { cp *= __cosf(h[i]); m[i] = cp; }
    }

    uint4 mq;
    mq.x = cvtpk(m[0], m[1]); mq.y = cvtpk(m[2], m[3]);
    mq.z = cvtpk(m[4], m[5]); mq.w = cvtpk(m[6], m[7]);
    mws[t] = mq;

    float4* hr = (float4*)(hout + (size_t)t * 8);
    hr[0] = make_float4(h[0], h[1], h[2], h[3]);
    hr[1] = make_float4(h[4], h[5], h[6], h[7]);
}

// ---------------- main: 64 tokens/block, 4 waves f-split, pure FFN ----------------
__global__ __launch_bounds__(256) void tbq_mfma(
    const float* __restrict__ b2,
    const float* __restrict__ g2,
    const float* __restrict__ beta2,
    const uint4* __restrict__ ws,
    float* __restrict__ out)
{
    __shared__ __align__(16) float part[4][64][8];   // 8KB per-wave partial ffn

    const int tid  = threadIdx.x;
    const int lane = tid & 63;
    const int wv   = tid >> 6;
    const int c    = lane & 15;
    const int g    = lane >> 4;
    const int t    = blockIdx.x * 64 + lane;

    const uint4* fw1 = ws + lane;
    const uint4* fw2 = ws + 8192 + lane;
    const uint4* mws = ws + 12288;
    const int cc0 = wv * 16;

    // ---- prefetch chunk 0 fragments ----
    FragU F0[2], F1[2], A2[2];
    F0[0].q = fw1[cc0 * 128];
    F1[0].q = fw1[cc0 * 128 + 64];
    A2[0].q = fw2[cc0 * 64];

    // ---- B1 fragments straight from global m (no barrier needed) ----
    FragU B1[4];
    #pragma unroll
    for (int T = 0; T < 4; ++T) {
        uint4 mr = mws[blockIdx.x * 64 + T * 16 + c];
        B1[T].u[0] = (g == 0) ? mr.x : ((g == 1) ? 0x00003F80u : 0u);  // k=8 bias row: 1.0
        B1[T].u[1] = (g == 0) ? mr.y : 0u;
        B1[T].u[2] = (g == 0) ? mr.z : 0u;
        B1[T].u[3] = (g == 0) ? mr.w : 0u;
    }

    // ---- pinned zero C-tuple + packed-zero reg ----
    f32x4 z4 = {0.f, 0.f, 0.f, 0.f};
    asm volatile("" : "+v"(z4));
    unsigned zz = 0u;
    asm volatile("" : "+v"(zz));

    // ---- FFN: 16 chunks, 2-deep pipelined fragment loads ----
    f32x4 acc[4] = {{0,0,0,0},{0,0,0,0},{0,0,0,0},{0,0,0,0}};

    #pragma unroll
    for (int i = 0; i < 16; ++i) {
        const int cur = i & 1, nxt = cur ^ 1;
        if (i < 15) {
            F0[nxt].q = fw1[(cc0 + i + 1) * 128];
            F1[nxt].q = fw1[(cc0 + i + 1) * 128 + 64];
            A2[nxt].q = fw2[(cc0 + i + 1) * 64];
        }
        #pragma unroll
        for (int T = 0; T < 4; ++T) {
            f32x4 c0 = __builtin_amdgcn_mfma_f32_16x16x32_bf16(F0[cur].v, B1[T].v, z4, 0, 0, 0);
            f32x4 c1 = __builtin_amdgcn_mfma_f32_16x16x32_bf16(F1[cur].v, B1[T].v, z4, 0, 0, 0);
            FragU B2;
            B2.u[0] = pkrelu(cvtpk(c0[0], c0[1]), zz);
            B2.u[1] = pkrelu(cvtpk(c0[2], c0[3]), zz);
            B2.u[2] = pkrelu(cvtpk(c1[0], c1[1]), zz);
            B2.u[3] = pkrelu(cvtpk(c1[2], c1[3]), zz);
            acc[T] = __builtin_amdgcn_mfma_f32_16x16x32_bf16(A2[cur].v, B2.v, acc[T], 0, 0, 0);
        }
    }

    // ---- write partial fragments: part[wv][tok][e] ----
    if (g < 2) {
        #pragma unroll
        for (int T = 0; T < 4; ++T) {
            *(f32x4*)&part[wv][T * 16 + c][4 * g] = acc[T];
        }
    }
    __syncthreads();

    // ---- wave 0: reduce, read h from out (scratch), LN2, overwrite out ----
    if (wv == 0) {
        float ffnv[8];
        #pragma unroll
        for (int e = 0; e < 8; ++e)
            ffnv[e] = part[0][lane][e] + part[1][lane][e]
                    + part[2][lane][e] + part[3][lane][e];

        const float4* hr = (const float4*)(out + (size_t)t * 8);
        float4 ha = hr[0], hb = hr[1];
        float h[8] = {ha.x, ha.y, ha.z, ha.w, hb.x, hb.y, hb.z, hb.w};

        float o[8];
        float mu2 = 0.0f;
        #pragma unroll
        for (int i = 0; i < 8; ++i) { o[i] = h[i] + ffnv[i] + b2[i]; mu2 += o[i]; }
        mu2 *= 0.125f;
        float v2 = 0.0f;
        #pragma unroll
        for (int i = 0; i < 8; ++i) { float d = o[i] - mu2; v2 += d * d; }
        v2 *= 0.125f;
        float rs2 = rsqrtf(v2 + LN_EPS);

        float res[8];
        #pragma unroll
        for (int i = 0; i < 8; ++i) res[i] = (o[i] - mu2) * rs2 * g2[i] + beta2[i];

        float4* orow = (float4*)(out + (size_t)t * 8);
        orow[0] = make_float4(res[0], res[1], res[2], res[3]);
        orow[1] = make_float4(res[4], res[5], res[6], res[7]);
    }
}

extern "C" void kernel_launch(void* const* d_in, const int* in_sizes, int n_in,
                              void* d_out, int out_size, void* d_ws, size_t ws_size,
                              hipStream_t stream) {
    const float* x     = (const float*)d_in[0];
    const float* Wq    = (const float*)d_in[1];
    const float* Wo    = (const float*)d_in[2];
    const float* W1    = (const float*)d_in[3];
    const float* b1    = (const float*)d_in[4];
    const float* W2    = (const float*)d_in[5];
    const float* b2    = (const float*)d_in[6];
    const float* g1    = (const float*)d_in[7];
    const float* beta1 = (const float*)d_in[8];
    const float* g2    = (const float*)d_in[9];
    const float* beta2 = (const float*)d_in[10];
    float* out = (float*)d_out;
    uint4* ws = (uint4*)d_ws;   // frags 192KB + m 2MB = 2.25MB

    const int ntok = in_sizes[0] / 8;      // 131072

    tbq_prep<<<48, 256, 0, stream>>>(W1, b1, W2, ws);
    tbq_prefix<<<ntok / 64, 64, 0, stream>>>(x, Wq, Wo, g1, beta1, ws + 12288, out);
    tbq_mfma<<<ntok / 64, 256, 0, stream>>>(b2, g2, beta2, ws, out);
}

// Round 9
// 37.797 us; speedup vs baseline: 1.0220x; 1.0220x over previous
//
#include <hip/hip_runtime.h>
#include <hip/hip_bf16.h>

#define FFN 2048
#define LN_EPS 1e-5f

typedef __attribute__((ext_vector_type(8))) short bf16x8;
typedef __attribute__((ext_vector_type(4))) float f32x4;

union FragU { bf16x8 v; unsigned u[4]; uint4 q; };

static __device__ __forceinline__ unsigned cvtpk(float lo, float hi) {
    unsigned r;
    asm("v_cvt_pk_bf16_f32 %0, %1, %2" : "=v"(r) : "v"(lo), "v"(hi));
    return r;
}

// relu on a packed bf16 pair: sign bit position matches f16; |x| << f16-NaN range
static __device__ __forceinline__ unsigned pkrelu(unsigned a, unsigned z) {
    unsigned r;
    asm("v_pk_max_f16 %0, %1, %2" : "=v"(r) : "v"(a), "v"(z));
    return r;
}

static __device__ __forceinline__ ushort to_bf16(float f) {   // RNE, finite inputs
    unsigned u = __float_as_uint(f);
    u += 0x7fffu + ((u >> 16) & 1u);
    return (ushort)(u >> 16);
}

// ---------------- prep: packed per-lane 16x16x32 fragments (R3-R8-verified values) --------
// ws uint4 layout, "record" = 33 uint4s: slot 0 = zeros (broadcast target for inactive
// lanes), slots 1..32 = the 32 real lanes.
//  pW1: rec = cc*2+s at base rec*33           (l32=slot-1: c=l32&15, g=l32>>4 in {0,1};
//       f = cc*32+s*16+c; g0: W1[f][j], g1: j==0 ? b1[f] : 0)
//  pW2: rec = cc at base 4224 + cc*33         (l32=slot-1: g=l32>>3, c=l32&7;
//       v[j] = W2[c*FFN + cc*32 + 4g + (j&3) + 16*(j>>2)])
// total 6336 uint4 = 101.4 KB
__global__ __launch_bounds__(256) void tbq_prep(
    const float* __restrict__ W1, const float* __restrict__ b1,
    const float* __restrict__ W2, uint4* __restrict__ ws)
{
    const int idx = blockIdx.x * 256 + threadIdx.x;
    if (idx >= 6336) return;
    ushort v[8] = {0,0,0,0,0,0,0,0};
    if (idx < 4224) {
        const int rec = idx / 33, r = idx % 33;
        if (r) {
            const int l32 = r - 1, c = l32 & 15, g = l32 >> 4;
            const int s = rec & 1, cc = rec >> 1;
            const int f = cc * 32 + s * 16 + c;
            if (g == 0) {
                #pragma unroll
                for (int j = 0; j < 8; ++j) v[j] = to_bf16(W1[f * 8 + j]);
            } else {
                v[0] = to_bf16(b1[f]);
            }
        }
    } else {
        const int i2 = idx - 4224;
        const int rec = i2 / 33, r = i2 % 33;
        if (r) {
            const int l32 = r - 1, g = l32 >> 3, c = l32 & 7, cc = rec;
            #pragma unroll
            for (int j = 0; j < 8; ++j) {
                const int fl = 4 * g + (j & 3) + 16 * (j >> 2);
                v[j] = to_bf16(W2[c * FFN + cc * 32 + fl]);
            }
        }
    }
    union { ushort s[8]; uint4 q; } pk;
    #pragma unroll
    for (int j = 0; j < 8; ++j) pk.s[j] = v[j];
    ws[idx] = pk.q;
}

// ---------------- main: 128 tokens/block, 4 waves f-split, in-kernel prefix ----------------
__global__ __launch_bounds__(256) void tbq_mfma(
    const float* __restrict__ x,
    const float* __restrict__ Wq,
    const float* __restrict__ Wo,
    const float* __restrict__ b2,
    const float* __restrict__ g1,
    const float* __restrict__ beta1,
    const float* __restrict__ g2,
    const float* __restrict__ beta2,
    const uint4* __restrict__ ws,
    float* __restrict__ out)
{
    __shared__ __align__(16) uint4 mS[128];           // 2KB  m (bf16) per token
    __shared__ __align__(16) float part[4][128][8];   // 16KB per-wave partial ffn

    const int tid  = threadIdx.x;
    const int lane = tid & 63;
    const int wv   = tid >> 6;
    const int c    = lane & 15;
    const int g    = lane >> 4;
    const int tok0 = blockIdx.x * 128;

    // per-lane packed-fragment slot offsets (uint4 units; 0 -> record zero slot)
    const int o1 = (lane < 32) ? (1 + lane) : 0;
    const int o2 = ((lane & 8) == 0) ? (1 + ((lane >> 4) << 3) + (lane & 7)) : 0;

    // ---- prefix: waves 0-1, one thread per token ----
    float h[8];
    if (tid < 128) {
        const int t = tok0 + tid;
        const float4* xr = (const float4*)(x + (size_t)t * 8);
        float4 xa = xr[0], xb = xr[1];
        float xv[8] = {xa.x, xa.y, xa.z, xa.w, xb.x, xb.y, xb.z, xb.w};

        float qm[8];
        {
            float cp = 1.0f;
            #pragma unroll
            for (int f = 0; f < 8; ++f) {
                float acc = 0.0f;
                #pragma unroll
                for (int e = 0; e < 8; ++e) acc += xv[e] * Wq[f * 8 + e];
                cp *= __cosf(acc);
                qm[f] = cp;
            }
        }
        float mu = 0.0f;
        #pragma unroll
        for (int f = 0; f < 8; ++f) {
            float acc = 0.0f;
            #pragma unroll
            for (int e = 0; e < 8; ++e) acc += qm[e] * Wo[f * 8 + e];
            h[f] = xv[f] + acc;
            mu += h[f];
        }
        mu *= 0.125f;
        float var = 0.0f;
        #pragma unroll
        for (int i = 0; i < 8; ++i) { float d = h[i] - mu; var += d * d; }
        var *= 0.125f;
        float rs = rsqrtf(var + LN_EPS);
        #pragma unroll
        for (int i = 0; i < 8; ++i) h[i] = (h[i] - mu) * rs * g1[i] + beta1[i];

        float m[8];
        {
            float cp = 1.0f;
            #pragma unroll
            for (int i = 0; i < 8; ++i) { cp *= __cosf(h[i]); m[i] = cp; }
        }
        uint4 mq;
        mq.x = cvtpk(m[0], m[1]); mq.y = cvtpk(m[2], m[3]);
        mq.z = cvtpk(m[4], m[5]); mq.w = cvtpk(m[6], m[7]);
        mS[tid] = mq;
    }
    __syncthreads();

    // ---- B1 fragments: 8 token-tiles (k=8g+j; g0: m, g1 j0: 1.0 bias row) ----
    FragU B1[8];
    #pragma unroll
    for (int T = 0; T < 8; ++T) {
        uint4 mr = mS[T * 16 + c];
        B1[T].u[0] = (g == 0) ? mr.x : ((g == 1) ? 0x00003F80u : 0u);
        B1[T].u[1] = (g == 0) ? mr.y : 0u;
        B1[T].u[2] = (g == 0) ? mr.z : 0u;
        B1[T].u[3] = (g == 0) ? mr.w : 0u;
    }

    // ---- pinned zero C-tuple + packed-zero reg ----
    f32x4 z4 = {0.f, 0.f, 0.f, 0.f};
    asm volatile("" : "+v"(z4));
    unsigned zz = 0u;
    asm volatile("" : "+v"(zz));

    // ---- FFN: 16 chunks of 32 f for this wave's range ----
    f32x4 acc[8] = {{0,0,0,0},{0,0,0,0},{0,0,0,0},{0,0,0,0},
                    {0,0,0,0},{0,0,0,0},{0,0,0,0},{0,0,0,0}};
    const int cc0 = wv * 16;

    #pragma unroll 4
    for (int i = 0; i < 16; ++i) {
        const int cc = cc0 + i;
        const uint4* r0 = ws + cc * 66;          // pW1 rec (s=0)
        const uint4* r1 = r0 + 33;               // pW1 rec (s=1)
        const uint4* r2 = ws + 4224 + cc * 33;   // pW2 rec
        FragU F0, F1, A2;
        F0.q = r0[o1];
        F1.q = r1[o1];
        A2.q = r2[o2];

        #pragma unroll
        for (int T = 0; T < 8; ++T) {
            f32x4 c0 = __builtin_amdgcn_mfma_f32_16x16x32_bf16(F0.v, B1[T].v, z4, 0, 0, 0);
            f32x4 c1 = __builtin_amdgcn_mfma_f32_16x16x32_bf16(F1.v, B1[T].v, z4, 0, 0, 0);
            FragU B2;
            B2.u[0] = pkrelu(cvtpk(c0[0], c0[1]), zz);
            B2.u[1] = pkrelu(cvtpk(c0[2], c0[3]), zz);
            B2.u[2] = pkrelu(cvtpk(c1[0], c1[1]), zz);
            B2.u[3] = pkrelu(cvtpk(c1[2], c1[3]), zz);
            acc[T] = __builtin_amdgcn_mfma_f32_16x16x32_bf16(A2.v, B2.v, acc[T], 0, 0, 0);
        }
    }

    // ---- write partial fragments: part[wv][tok][e] ----
    if (g < 2) {
        #pragma unroll
        for (int T = 0; T < 8; ++T) {
            *(f32x4*)&part[wv][T * 16 + c][4 * g] = acc[T];
        }
    }
    __syncthreads();

    // ---- waves 0-1: reduce partials + LN2 + store (token = tok0 + tid) ----
    if (tid < 128) {
        float ffnv[8];
        #pragma unroll
        for (int e = 0; e < 8; ++e)
            ffnv[e] = part[0][tid][e] + part[1][tid][e]
                    + part[2][tid][e] + part[3][tid][e];

        float o[8];
        float mu2 = 0.0f;
        #pragma unroll
        for (int i = 0; i < 8; ++i) { o[i] = h[i] + ffnv[i] + b2[i]; mu2 += o[i]; }
        mu2 *= 0.125f;
        float v2 = 0.0f;
        #pragma unroll
        for (int i = 0; i < 8; ++i) { float d = o[i] - mu2; v2 += d * d; }
        v2 *= 0.125f;
        float rs2 = rsqrtf(v2 + LN_EPS);

        float res[8];
        #pragma unroll
        for (int i = 0; i < 8; ++i) res[i] = (o[i] - mu2) * rs2 * g2[i] + beta2[i];

        float4* orow = (float4*)(out + (size_t)(tok0 + tid) * 8);
        orow[0] = make_float4(res[0], res[1], res[2], res[3]);
        orow[1] = make_float4(res[4], res[5], res[6], res[7]);
    }
}

extern "C" void kernel_launch(void* const* d_in, const int* in_sizes, int n_in,
                              void* d_out, int out_size, void* d_ws, size_t ws_size,
                              hipStream_t stream) {
    const float* x     = (const float*)d_in[0];
    const float* Wq    = (const float*)d_in[1];
    const float* Wo    = (const float*)d_in[2];
    const float* W1    = (const float*)d_in[3];
    const float* b1    = (const float*)d_in[4];
    const float* W2    = (const float*)d_in[5];
    const float* b2    = (const float*)d_in[6];
    const float* g1    = (const float*)d_in[7];
    const float* beta1 = (const float*)d_in[8];
    const float* g2    = (const float*)d_in[9];
    const float* beta2 = (const float*)d_in[10];
    float* out = (float*)d_out;
    uint4* ws = (uint4*)d_ws;   // 6336*16 = 101.4 KB

    tbq_prep<<<25, 256, 0, stream>>>(W1, b1, W2, ws);

    const int ntok = in_sizes[0] / 8;      // 131072
    const int grid = ntok / 128;           // 1024 blocks, 4 waves f-split
    tbq_mfma<<<grid, 256, 0, stream>>>(x, Wq, Wo, b2, g1, beta1, g2, beta2, ws, out);
}

// Round 11
// 35.959 us; speedup vs baseline: 1.0742x; 1.0511x over previous
//
#include <hip/hip_runtime.h>
#include <hip/hip_bf16.h>

#define FFN 2048
#define LN_EPS 1e-5f

typedef __attribute__((ext_vector_type(8))) short bf16x8;
typedef __attribute__((ext_vector_type(4))) float f32x4;

union FragU { bf16x8 v; unsigned u[4]; uint4 q; };

static __device__ __forceinline__ unsigned cvtpk(float lo, float hi) {
    unsigned r;
    asm("v_cvt_pk_bf16_f32 %0, %1, %2" : "=v"(r) : "v"(lo), "v"(hi));
    return r;
}

// relu on packed bf16 pair (src1 = inline constant 0: both halves zero)
static __device__ __forceinline__ unsigned pkrelu(unsigned a) {
    unsigned r;
    asm("v_pk_max_f16 %0, %1, 0" : "=v"(r) : "v"(a));
    return r;
}

static __device__ __forceinline__ ushort to_bf16(float f) {   // RNE, finite inputs
    unsigned u = __float_as_uint(f);
    u += 0x7fffu + ((u >> 16) & 1u);
    return (ushort)(u >> 16);
}

// ---------------- prep: packed per-lane 16x16x32 fragments (R3-R9-verified values) --------
// record = 33 uint4: slot0 = zeros (inactive-lane broadcast), slots 1..32 = real lanes.
//  pW1: rec = cc*2+s at rec*33      (l32: c=l32&15, g=l32>>4; f=cc*32+s*16+c;
//                                    g0: W1[f][j], g1: j==0 ? b1[f] : 0)
//  pW2: rec = cc at 4224+cc*33      (l32: g=l32>>3, c=l32&7;
//                                    v[j] = W2[c*FFN + cc*32 + 4g + (j&3) + 16*(j>>2)])
__global__ __launch_bounds__(256) void tbq_prep(
    const float* __restrict__ W1, const float* __restrict__ b1,
    const float* __restrict__ W2, uint4* __restrict__ ws)
{
    const int idx = blockIdx.x * 256 + threadIdx.x;
    if (idx >= 6336) return;
    ushort v[8] = {0,0,0,0,0,0,0,0};
    if (idx < 4224) {
        const int rec = idx / 33, r = idx % 33;
        if (r) {
            const int l32 = r - 1, c = l32 & 15, g = l32 >> 4;
            const int s = rec & 1, cc = rec >> 1;
            const int f = cc * 32 + s * 16 + c;
            if (g == 0) {
                #pragma unroll
                for (int j = 0; j < 8; ++j) v[j] = to_bf16(W1[f * 8 + j]);
            } else {
                v[0] = to_bf16(b1[f]);
            }
        }
    } else {
        const int i2 = idx - 4224;
        const int rec = i2 / 33, r = i2 % 33;
        if (r) {
            const int l32 = r - 1, g = l32 >> 3, c = l32 & 7, cc = rec;
            #pragma unroll
            for (int j = 0; j < 8; ++j) {
                const int fl = 4 * g + (j & 3) + 16 * (j >> 2);
                v[j] = to_bf16(W2[c * FFN + cc * 32 + fl]);
            }
        }
    }
    union { ushort s[8]; uint4 q; } pk;
    #pragma unroll
    for (int j = 0; j < 8; ++j) pk.s[j] = v[j];
    ws[idx] = pk.q;
}

// ---------------- main: 128 tokens/block, 4 waves f-split, 4-slot/dist-3 pipeline ----------
__global__ __launch_bounds__(256) void tbq_mfma(
    const float* __restrict__ x,
    const float* __restrict__ Wq,
    const float* __restrict__ Wo,
    const float* __restrict__ b2,
    const float* __restrict__ g1,
    const float* __restrict__ beta1,
    const float* __restrict__ g2,
    const float* __restrict__ beta2,
    const uint4* __restrict__ ws,
    float* __restrict__ out)
{
    __shared__ __align__(16) uint4 mS[128];           // 2KB  m (bf16) per token
    __shared__ __align__(16) float part[4][128][8];   // 16KB per-wave partial ffn

    const int tid  = threadIdx.x;
    const int lane = tid & 63;
    const int wv   = tid >> 6;
    const int c    = lane & 15;
    const int g    = lane >> 4;
    const int tok0 = blockIdx.x * 128;

    // per-lane packed-record slot offsets (uint4 units; 0 -> zero slot)
    const int o1 = (lane < 32) ? (1 + lane) : 0;
    const int o2 = ((lane & 8) == 0) ? (1 + ((lane >> 4) << 3) + (lane & 7)) : 0;

    const int cc0 = wv * 16;

    // ---- pipeline prologue: issue loads for chunks 0,1,2 into slots 0,1,2 ----
    FragU F0[4], F1[4], A2[4];
    #pragma unroll
    for (int p = 0; p < 3; ++p) {
        const int cc = cc0 + p;
        F0[p].q = (ws + cc * 66)[o1];
        F1[p].q = (ws + cc * 66 + 33)[o1];
        A2[p].q = (ws + 4224 + cc * 33)[o2];
    }

    // ---- prefix: threads 0-127, one thread per token (overlaps the frag loads) ----
    float h[8];
    if (tid < 128) {
        const int t = tok0 + tid;
        const float4* xr = (const float4*)(x + (size_t)t * 8);
        float4 xa = xr[0], xb = xr[1];
        float xv[8] = {xa.x, xa.y, xa.z, xa.w, xb.x, xb.y, xb.z, xb.w};

        float qm[8];
        {
            float cp = 1.0f;
            #pragma unroll
            for (int f = 0; f < 8; ++f) {
                float acc = 0.0f;
                #pragma unroll
                for (int e = 0; e < 8; ++e) acc += xv[e] * Wq[f * 8 + e];
                cp *= __cosf(acc);
                qm[f] = cp;
            }
        }
        float mu = 0.0f;
        #pragma unroll
        for (int f = 0; f < 8; ++f) {
            float acc = 0.0f;
            #pragma unroll
            for (int e = 0; e < 8; ++e) acc += qm[e] * Wo[f * 8 + e];
            h[f] = xv[f] + acc;
            mu += h[f];
        }
        mu *= 0.125f;
        float var = 0.0f;
        #pragma unroll
        for (int i = 0; i < 8; ++i) { float d = h[i] - mu; var += d * d; }
        var *= 0.125f;
        float rs = rsqrtf(var + LN_EPS);
        #pragma unroll
        for (int i = 0; i < 8; ++i) h[i] = (h[i] - mu) * rs * g1[i] + beta1[i];

        float m[8];
        {
            float cp = 1.0f;
            #pragma unroll
            for (int i = 0; i < 8; ++i) { cp *= __cosf(h[i]); m[i] = cp; }
        }
        uint4 mq;
        mq.x = cvtpk(m[0], m[1]); mq.y = cvtpk(m[2], m[3]);
        mq.z = cvtpk(m[4], m[5]); mq.w = cvtpk(m[6], m[7]);
        mS[tid] = mq;
    }
    __syncthreads();

    // ---- B1 fragments: 8 token-tiles (k=8g+j; g0: m, g1 j0: bias row 1.0) ----
    FragU B1[8];
    #pragma unroll
    for (int T = 0; T < 8; ++T) {
        uint4 mr = mS[T * 16 + c];
        B1[T].u[0] = (g == 0) ? mr.x : ((g == 1) ? 0x00003F80u : 0u);
        B1[T].u[1] = (g == 0) ? mr.y : 0u;
        B1[T].u[2] = (g == 0) ? mr.z : 0u;
        B1[T].u[3] = (g == 0) ? mr.w : 0u;
    }

    // ---- pinned zero C-tuple ----
    f32x4 z4 = {0.f, 0.f, 0.f, 0.f};
    asm volatile("" : "+v"(z4));

    // ---- FFN: 16 chunks, 4-slot rotation / distance-3 prefetch ----
    f32x4 acc[8] = {{0,0,0,0},{0,0,0,0},{0,0,0,0},{0,0,0,0},
                    {0,0,0,0},{0,0,0,0},{0,0,0,0},{0,0,0,0}};

    #pragma unroll
    for (int i = 0; i < 16; ++i) {
        const int cur = i & 3;
        if (i + 3 < 16) {
            const int nslot = (i + 3) & 3;   // != cur; was consumed at iter i-1
            const int cc = cc0 + i + 3;
            F0[nslot].q = (ws + cc * 66)[o1];
            F1[nslot].q = (ws + cc * 66 + 33)[o1];
            A2[nslot].q = (ws + 4224 + cc * 33)[o2];
        }
        __builtin_amdgcn_s_setprio(1);
        #pragma unroll
        for (int T = 0; T < 8; ++T) {
            f32x4 c0 = __builtin_amdgcn_mfma_f32_16x16x32_bf16(F0[cur].v, B1[T].v, z4, 0, 0, 0);
            f32x4 c1 = __builtin_amdgcn_mfma_f32_16x16x32_bf16(F1[cur].v, B1[T].v, z4, 0, 0, 0);
            FragU B2;
            B2.u[0] = pkrelu(cvtpk(c0[0], c0[1]));
            B2.u[1] = pkrelu(cvtpk(c0[2], c0[3]));
            B2.u[2] = pkrelu(cvtpk(c1[0], c1[1]));
            B2.u[3] = pkrelu(cvtpk(c1[2], c1[3]));
            acc[T] = __builtin_amdgcn_mfma_f32_16x16x32_bf16(A2[cur].v, B2.v, acc[T], 0, 0, 0);
        }
        __builtin_amdgcn_s_setprio(0);
    }

    // ---- write partial fragments: part[wv][tok][e] ----
    if (g < 2) {
        #pragma unroll
        for (int T = 0; T < 8; ++T) {
            *(f32x4*)&part[wv][T * 16 + c][4 * g] = acc[T];
        }
    }
    __syncthreads();

    // ---- threads 0-127: reduce partials + LN2 + store ----
    if (tid < 128) {
        float ffnv[8];
        #pragma unroll
        for (int e = 0; e < 8; ++e)
            ffnv[e] = part[0][tid][e] + part[1][tid][e]
                    + part[2][tid][e] + part[3][tid][e];

        float o[8];
        float mu2 = 0.0f;
        #pragma unroll
        for (int i = 0; i < 8; ++i) { o[i] = h[i] + ffnv[i] + b2[i]; mu2 += o[i]; }
        mu2 *= 0.125f;
        float v2 = 0.0f;
        #pragma unroll
        for (int i = 0; i < 8; ++i) { float d = o[i] - mu2; v2 += d * d; }
        v2 *= 0.125f;
        float rs2 = rsqrtf(v2 + LN_EPS);

        float res[8];
        #pragma unroll
        for (int i = 0; i < 8; ++i) res[i] = (o[i] - mu2) * rs2 * g2[i] + beta2[i];

        float4* orow = (float4*)(out + (size_t)(tok0 + tid) * 8);
        orow[0] = make_float4(res[0], res[1], res[2], res[3]);
        orow[1] = make_float4(res[4], res[5], res[6], res[7]);
    }
}

extern "C" void kernel_launch(void* const* d_in, const int* in_sizes, int n_in,
                              void* d_out, int out_size, void* d_ws, size_t ws_size,
                              hipStream_t stream) {
    const float* x     = (const float*)d_in[0];
    const float* Wq    = (const float*)d_in[1];
    const float* Wo    = (const float*)d_in[2];
    const float* W1    = (const float*)d_in[3];
    const float* b1    = (const float*)d_in[4];
    const float* W2    = (const float*)d_in[5];
    const float* b2    = (const float*)d_in[6];
    const float* g1    = (const float*)d_in[7];
    const float* beta1 = (const float*)d_in[8];
    const float* g2    = (const float*)d_in[9];
    const float* beta2 = (const float*)d_in[10];
    float* out = (float*)d_out;
    uint4* ws = (uint4*)d_ws;   // 6336*16 = 101.4 KB

    tbq_prep<<<25, 256, 0, stream>>>(W1, b1, W2, ws);

    const int ntok = in_sizes[0] / 8;      // 131072
    const int grid = ntok / 128;           // 1024 blocks, 4 waves f-split
    tbq_mfma<<<grid, 256, 0, stream>>>(x, Wq, Wo, b2, g1, beta1, g2, beta2, ws, out);
}